// Round 4
// baseline (239.495 us; speedup 1.0000x reference)
//
#include <hip/hip_runtime.h>

constexpr int B = 1024, N = 40, K = 32, NA = 10;
constexpr int NPAIR = 780;     // 40 choose 2
constexpr int ZP = 36;         // padded z row stride

// =================== kernel 1: per-molecule cluster + z + atom head ===================
// block = molecule. Phases: cluster head (1 row) -> log_pi ; z sample (40 threads);
// atom h (5120 units (n,j)); atom out (400 units (n,k)).
__global__ __launch_bounds__(256, 4) void mol_kernel(
    const float* __restrict__ eta, const float* __restrict__ gumbel,
    const float* __restrict__ z_noise,
    const float* __restrict__ cW1, const float* __restrict__ cb1,
    const float* __restrict__ cW2, const float* __restrict__ cb2,
    const float* __restrict__ cWs, const float* __restrict__ cbs,
    const float* __restrict__ means, const float* __restrict__ lsig,
    const float* __restrict__ aW1, const float* __restrict__ ab1,
    const float* __restrict__ aW2, const float* __restrict__ ab2,
    const float* __restrict__ aWs, const float* __restrict__ abs_,
    float* __restrict__ zbuf, float* __restrict__ atom_out)
{
  __shared__ __align__(16) float Zs[N * ZP];      // 5760 B
  __shared__ __align__(16) float hbuf[N * 132];   // 21120 B
  __shared__ float etas[64];
  __shared__ float hcl[128];
  __shared__ float lps[32];
  const int tid = threadIdx.x;
  const int m = blockIdx.x;

  if (tid < 64) etas[tid] = eta[m * 64 + tid];
  __syncthreads();

  // cluster h (128 units)
  if (tid < 128) {
    float h = cb1[tid];
    #pragma unroll 8
    for (int d = 0; d < 64; ++d) h += etas[d] * cW1[d * 128 + tid];
    hcl[tid] = fmaxf(h, 0.f);
  }
  __syncthreads();

  // cluster logits + log-softmax (32 lanes of wave 0)
  if (tid < 32) {
    float x = cb2[tid] + cbs[tid];
    #pragma unroll 8
    for (int j = 0; j < 128; ++j) x += hcl[j] * cW2[j * 32 + tid];
    #pragma unroll 8
    for (int d = 0; d < 64; ++d) x += etas[d] * cWs[d * 32 + tid];
    float mx = x;
    for (int off = 16; off; off >>= 1) mx = fmaxf(mx, __shfl_xor(mx, off));
    float e = __expf(x - mx);
    float s = e;
    for (int off = 16; off; off >>= 1) s += __shfl_xor(s, off);
    lps[tid] = (x - mx) - __logf(s);
  }
  __syncthreads();

  // z sample: thread per node
  if (tid < 40) {
    const int n = m * 40 + tid;
    float g[32];
    const float4* g4 = (const float4*)(gumbel + (size_t)n * 32);
    #pragma unroll
    for (int q = 0; q < 8; ++q) {
      float4 v = g4[q];
      g[4*q] = v.x; g[4*q+1] = v.y; g[4*q+2] = v.z; g[4*q+3] = v.w;
    }
    int kb = 0; float vb = lps[0] + g[0];
    #pragma unroll
    for (int c = 1; c < 32; ++c) {
      float v = lps[c] + g[c];
      if (v > vb) { vb = v; kb = c; }   // first-index tie-break
    }
    const float4* zn4 = (const float4*)(z_noise + (size_t)n * 32);
    const float4* mk4 = (const float4*)(means + kb * 32);
    const float4* ls4 = (const float4*)(lsig + kb * 32);
    float4* zg4 = (float4*)(zbuf + (size_t)n * 32);
    float4* zl4 = (float4*)&Zs[tid * ZP];
    #pragma unroll
    for (int q = 0; q < 8; ++q) {
      float4 zn = zn4[q], mk = mk4[q], ls = ls4[q];
      float4 zz;
      zz.x = zn.x * __expf(fminf(fmaxf(ls.x, -20.f), 30.f)) + mk.x;
      zz.y = zn.y * __expf(fminf(fmaxf(ls.y, -20.f), 30.f)) + mk.y;
      zz.z = zn.z * __expf(fminf(fmaxf(ls.z, -20.f), 30.f)) + mk.z;
      zz.w = zn.w * __expf(fminf(fmaxf(ls.w, -20.f), 30.f)) + mk.w;
      zl4[q] = zz; zg4[q] = zz;
    }
  }
  __syncthreads();

  // atom h: unit (n, j), 5120 units, 20 iters, coalesced aW1 column reads
  for (int it = 0; it < 20; ++it) {
    const int u = tid + it * 256;
    const int n = u >> 7, j = u & 127;
    const float* zrow = &Zs[n * ZP];
    float h = ab1[j];
    #pragma unroll 8
    for (int c = 0; c < 32; ++c) h += zrow[c] * aW1[c * 128 + j];
    hbuf[n * 132 + j] = fmaxf(h, 0.f);
  }
  __syncthreads();

  // atom out: unit (n, k), 400 units
  for (int it = 0; it < 2; ++it) {
    const int u = tid + it * 256;
    if (u < 400) {
      const int n = u / 10, k = u - n * 10;
      const float* zrow = &Zs[n * ZP];
      const float* hrow = &hbuf[n * 132];
      float acc = ab2[k] + abs_[k];
      #pragma unroll 8
      for (int c = 0; c < 32; ++c) acc += zrow[c] * aWs[c * 10 + k];
      #pragma unroll 8
      for (int j = 0; j < 128; ++j) acc += hrow[j] * aW2[j * 10 + k];
      atom_out[(size_t)m * 400 + u] = acc;
    }
  }
}

// =================== kernel 2: per-molecule bilinear (tiled U) + edge head ===================
__global__ __launch_bounds__(256, 4) void edge_kernel(
    const float* __restrict__ zbuf, const float* __restrict__ bond,
    const float* __restrict__ bW1, const float* __restrict__ bb1,
    const float* __restrict__ bW2, const float* __restrict__ bb2,
    const float* __restrict__ bWs, const float* __restrict__ bbs,
    float* __restrict__ edge_out)
{
  __shared__ __align__(16) float Zs[N * ZP];        // 5760 B
  __shared__ __align__(16) float Wsym[5 * 1156];    // 23120 B, plane stride 1156, row stride 36
  __shared__ __align__(16) float Ut[5 * 8 * ZP];    // 5760 B : U tile, rows (t, ii)
  __shared__ __align__(16) float hw[744];           // head weights
  const int tid = threadIdx.x;
  const int m = blockIdx.x;

  // ---- stage Zs (float4), Wsym (symmetrized), head weights ----
  for (int e = tid; e < 320; e += 256) {
    int i = e >> 3, q = e & 7;
    ((float4*)&Zs[i * ZP])[q] = ((const float4*)(zbuf + (size_t)(m * 40 + i) * 32))[q];
  }
  for (int e = tid; e < 5120; e += 256) {
    int t = e >> 10, r = e & 1023, c = r >> 5, d = r & 31;
    Wsym[t * 1156 + c * ZP + d] = 0.5f * (bond[t * 1024 + c * 32 + d] + bond[t * 1024 + d * 32 + c]);
  }
  // hw layout: w1h[320]@0, b1h[64]@320, w2t[320]@384 (bW2^T), b2h[5]@704, wsh[25]@709, bsh[5]@734
  for (int idx = tid; idx < 739; idx += 256) {
    if (idx < 320) hw[idx] = bW1[idx];
    else if (idx < 384) hw[idx] = bb1[idx - 320];
    else if (idx < 704) { int q = idx - 384; int t2 = q >> 6, j = q & 63; hw[384 + t2 * 64 + j] = bW2[j * 5 + t2]; }
    else if (idx < 709) hw[idx] = bb2[idx - 704];
    else if (idx < 734) hw[idx] = bWs[idx - 709];
    else hw[idx] = bbs[idx - 734];
  }
  __syncthreads();

  // ---- tiles: tile T covers i in {T, T+5, ..., T+35}; counts 172-8T <= 256 ----
  float bil[5][5];
  int pglob[5];
  #pragma unroll
  for (int T = 0; T < 5; ++T) {
    // U tile: 160 units (t, ii, quarter)
    if (tid < 160) {
      const int t = tid >> 5, r = tid & 31, ii = r >> 2, q2 = r & 3;
      const int i = ii * 5 + T;
      float zr[32];
      const float4* z4 = (const float4*)&Zs[i * ZP];
      #pragma unroll
      for (int q = 0; q < 8; ++q) {
        float4 v = z4[q];
        zr[4*q] = v.x; zr[4*q+1] = v.y; zr[4*q+2] = v.z; zr[4*q+3] = v.w;
      }
      float4 a0 = make_float4(0.f,0.f,0.f,0.f), a1 = a0;
      const float* wbase = &Wsym[t * 1156 + q2 * 8];
      #pragma unroll 8
      for (int c = 0; c < 32; ++c) {
        const float4* w4 = (const float4*)(wbase + c * ZP);
        float4 w0 = w4[0], w1 = w4[1];
        float zc = zr[c];
        a0.x += zc*w0.x; a0.y += zc*w0.y; a0.z += zc*w0.z; a0.w += zc*w0.w;
        a1.x += zc*w1.x; a1.y += zc*w1.y; a1.z += zc*w1.z; a1.w += zc*w1.w;
      }
      float4* u4 = (float4*)&Ut[(t * 8 + ii) * ZP + q2 * 8];
      u4[0] = a0; u4[1] = a1;
    }
    __syncthreads();

    // bilinear for this tile's pairs (<= 172 threads active)
    const int tcnt = 172 - 8 * T;
    if (tid < tcnt) {
      int ii = 0, rem = tid;
      while (rem >= 39 - (ii * 5 + T)) { rem -= 39 - (ii * 5 + T); ++ii; }
      const int i = ii * 5 + T;
      const int j = i + 1 + rem;
      pglob[T] = i * (79 - i) / 2 + (j - i - 1);
      float4 zj[8];
      const float4* zj4 = (const float4*)&Zs[j * ZP];
      #pragma unroll
      for (int q = 0; q < 8; ++q) zj[q] = zj4[q];
      #pragma unroll
      for (int t = 0; t < 5; ++t) {
        const float4* u4 = (const float4*)&Ut[(t * 8 + ii) * ZP];
        float s = 0.f;
        #pragma unroll
        for (int q = 0; q < 8; ++q) {
          float4 u = u4[q];
          s += u.x * zj[q].x + u.y * zj[q].y + u.z * zj[q].z + u.w * zj[q].w;
        }
        bil[T][t] = s;
      }
    } else {
      pglob[T] = -1;
      #pragma unroll
      for (int t = 0; t < 5; ++t) bil[T][t] = 0.f;
    }
    __syncthreads();   // before overwriting Ut next tile
  }

  // ---- head for the (<=5) owned pairs ----
  const float* w1h = hw;
  const float* b1h = hw + 320;
  const float* w2t = hw + 384;
  const float* b2h = hw + 704;
  const float* wsh = hw + 709;
  const float* bsh = hw + 734;

  float lg[5][5];
  #pragma unroll
  for (int T = 0; T < 5; ++T)
    #pragma unroll
    for (int t2 = 0; t2 < 5; ++t2) {
      float a = b2h[t2] + bsh[t2];
      #pragma unroll
      for (int t = 0; t < 5; ++t) a += bil[T][t] * wsh[t * 5 + t2];
      lg[T][t2] = a;
    }

  for (int j4 = 0; j4 < 16; ++j4) {
    float4 bb = ((const float4*)b1h)[j4];
    float4 w1v[5], w2v[5];
    #pragma unroll
    for (int t = 0; t < 5; ++t) {
      w1v[t] = ((const float4*)(w1h + t * 64))[j4];
      w2v[t] = ((const float4*)(w2t + t * 64))[j4];
    }
    #pragma unroll
    for (int T = 0; T < 5; ++T) {
      float4 h = bb;
      #pragma unroll
      for (int t = 0; t < 5; ++t) {
        float bt = bil[T][t];
        h.x += bt * w1v[t].x; h.y += bt * w1v[t].y; h.z += bt * w1v[t].z; h.w += bt * w1v[t].w;
      }
      h.x = fmaxf(h.x, 0.f); h.y = fmaxf(h.y, 0.f); h.z = fmaxf(h.z, 0.f); h.w = fmaxf(h.w, 0.f);
      #pragma unroll
      for (int t2 = 0; t2 < 5; ++t2)
        lg[T][t2] += h.x * w2v[t2].x + h.y * w2v[t2].y + h.z * w2v[t2].z + h.w * w2v[t2].w;
    }
  }

  #pragma unroll
  for (int T = 0; T < 5; ++T) {
    if (pglob[T] < 0) continue;
    float mx = lg[T][0];
    #pragma unroll
    for (int t2 = 1; t2 < 5; ++t2) mx = fmaxf(mx, lg[T][t2]);
    float e[5], s = 0.f;
    #pragma unroll
    for (int t2 = 0; t2 < 5; ++t2) { e[t2] = __expf(lg[T][t2] - mx); s += e[t2]; }
    float inv = 1.f / s;
    float* outp = edge_out + ((size_t)m * NPAIR + pglob[T]) * 5;
    #pragma unroll
    for (int t2 = 0; t2 < 5; ++t2) outp[t2] = e[t2] * inv;
  }
}

extern "C" void kernel_launch(void* const* d_in, const int* in_sizes, int n_in,
                              void* d_out, int out_size, void* d_ws, size_t ws_size,
                              hipStream_t stream) {
  const float* eta    = (const float*)d_in[0];
  const float* gumbel = (const float*)d_in[1];
  const float* z_noise= (const float*)d_in[2];
  const float* cW1 = (const float*)d_in[3];
  const float* cb1 = (const float*)d_in[4];
  const float* cW2 = (const float*)d_in[5];
  const float* cb2 = (const float*)d_in[6];
  const float* cWs = (const float*)d_in[7];
  const float* cbs = (const float*)d_in[8];
  const float* means = (const float*)d_in[9];
  const float* lsig  = (const float*)d_in[10];
  const float* aW1 = (const float*)d_in[11];
  const float* ab1 = (const float*)d_in[12];
  const float* aW2 = (const float*)d_in[13];
  const float* ab2 = (const float*)d_in[14];
  const float* aWs = (const float*)d_in[15];
  const float* abs_= (const float*)d_in[16];
  const float* bond= (const float*)d_in[17];
  const float* bW1 = (const float*)d_in[18];
  const float* bb1 = (const float*)d_in[19];
  const float* bW2 = (const float*)d_in[20];
  const float* bb2 = (const float*)d_in[21];
  const float* bWs = (const float*)d_in[22];
  const float* bbs = (const float*)d_in[23];

  float* zbuf = (float*)d_ws;                   // 40960*32 fp32 = 5.24 MB
  float* atom_out = (float*)d_out;              // 409600
  float* edge_out = atom_out + (size_t)B * N * NA;

  mol_kernel<<<B, 256, 0, stream>>>(eta, gumbel, z_noise,
                                    cW1, cb1, cW2, cb2, cWs, cbs,
                                    means, lsig, aW1, ab1, aW2, ab2, aWs, abs_,
                                    zbuf, atom_out);
  edge_kernel<<<B, 256, 0, stream>>>(zbuf, bond, bW1, bb1, bW2, bb2, bWs, bbs, edge_out);
}

// Round 5
// 211.078 us; speedup vs baseline: 1.1346x; 1.1346x over previous
//
#include <hip/hip_runtime.h>

constexpr int NPAIR = 780, NA = 10;
constexpr int ZTP = 44;                    // Zt / hT / Ut row stride (floats)
constexpr int WSR = 36, WSP = 1156, UTP = 1408;
constexpr int OFF_ZT = 0;                  // Zt[32][44]            1408
constexpr int OFF_A  = 1408;               // aliased big region
constexpr int OFF_HT = OFF_A;              // hT[128][44]           5632
constexpr int OFF_WS = OFF_A;              // Wsym[5][1156]         5780
constexpr int OFF_UT = OFF_A + 5 * WSP;    // Ut[5][1408]  @7188    7040 (ends 14228)
constexpr int OFF_BT = OFF_A;              // bilT[5][784] @1408    3920
constexpr int OFF_HW = OFF_A + 5 * 784;    // head weights @5328    744
constexpr int OFF_ET = 14228;              // etas[64]
constexpr int OFF_HC = 14292;              // hcl[128]
constexpr int OFF_LP = 14420;              // lps[32]
constexpr int SH_TOT = 14452;              // 57808 B -> 2 blocks/CU

__global__ __launch_bounds__(256, 2) void fused_kernel(
    const float* __restrict__ eta, const float* __restrict__ gumbel,
    const float* __restrict__ z_noise,
    const float* __restrict__ cW1, const float* __restrict__ cb1,
    const float* __restrict__ cW2, const float* __restrict__ cb2,
    const float* __restrict__ cWs, const float* __restrict__ cbs,
    const float* __restrict__ means, const float* __restrict__ lsig,
    const float* __restrict__ aW1, const float* __restrict__ ab1,
    const float* __restrict__ aW2, const float* __restrict__ ab2,
    const float* __restrict__ aWs, const float* __restrict__ abs_,
    const float* __restrict__ bond,
    const float* __restrict__ bW1, const float* __restrict__ bb1,
    const float* __restrict__ bW2, const float* __restrict__ bb2,
    const float* __restrict__ bWs, const float* __restrict__ bbs,
    float* __restrict__ atom_out, float* __restrict__ edge_out)
{
  __shared__ __align__(16) float S[SH_TOT];
  const int tid = threadIdx.x;
  const int m = blockIdx.x;

  // ---------- cluster head ----------
  if (tid < 64) S[OFF_ET + tid] = eta[m * 64 + tid];
  __syncthreads();

  if (tid < 128) {
    float h = cb1[tid];
    #pragma unroll 8
    for (int d = 0; d < 64; ++d) h += S[OFF_ET + d] * cW1[d * 128 + tid];
    S[OFF_HC + tid] = fmaxf(h, 0.f);
  }
  __syncthreads();

  if (tid < 32) {
    float x = cb2[tid] + cbs[tid];
    #pragma unroll 8
    for (int j = 0; j < 128; ++j) x += S[OFF_HC + j] * cW2[j * 32 + tid];
    #pragma unroll 8
    for (int d = 0; d < 64; ++d)  x += S[OFF_ET + d] * cWs[d * 32 + tid];
    float mx = x;
    for (int off = 16; off; off >>= 1) mx = fmaxf(mx, __shfl_xor(mx, off));
    float e = __expf(x - mx);
    float s = e;
    for (int off = 16; off; off >>= 1) s += __shfl_xor(s, off);
    S[OFF_LP + tid] = (x - mx) - __logf(s);
  }
  __syncthreads();

  // ---------- z sample -> Zt[c][n] ----------
  if (tid < 40) {
    const int n = m * 40 + tid;
    float g[32];
    const float4* g4 = (const float4*)(gumbel + (size_t)n * 32);
    #pragma unroll
    for (int q = 0; q < 8; ++q) {
      float4 v = g4[q];
      g[4*q] = v.x; g[4*q+1] = v.y; g[4*q+2] = v.z; g[4*q+3] = v.w;
    }
    int kb = 0; float vb = S[OFF_LP] + g[0];
    #pragma unroll
    for (int c = 1; c < 32; ++c) {
      float v = S[OFF_LP + c] + g[c];
      if (v > vb) { vb = v; kb = c; }   // first-index tie-break
    }
    const float4* zn4 = (const float4*)(z_noise + (size_t)n * 32);
    const float4* mk4 = (const float4*)(means + kb * 32);
    const float4* ls4 = (const float4*)(lsig + kb * 32);
    #pragma unroll
    for (int q = 0; q < 8; ++q) {
      float4 zn = zn4[q], mk = mk4[q], ls = ls4[q];
      float z0 = zn.x * __expf(fminf(fmaxf(ls.x, -20.f), 30.f)) + mk.x;
      float z1 = zn.y * __expf(fminf(fmaxf(ls.y, -20.f), 30.f)) + mk.y;
      float z2 = zn.z * __expf(fminf(fmaxf(ls.z, -20.f), 30.f)) + mk.z;
      float z3 = zn.w * __expf(fminf(fmaxf(ls.w, -20.f), 30.f)) + mk.w;
      S[OFF_ZT + (4*q    ) * ZTP + tid] = z0;
      S[OFF_ZT + (4*q + 1) * ZTP + tid] = z1;
      S[OFF_ZT + (4*q + 2) * ZTP + tid] = z2;
      S[OFF_ZT + (4*q + 3) * ZTP + tid] = z3;
    }
  }
  __syncthreads();

  // ---------- atom-h: 4n x 4j register tiles -> hT[j][n] ----------
  // 320 units: ng in [0,10) (4 nodes), jg in [0,32) (4 j)
  for (int u = tid; u < 320; u += 256) {
    const int ng = u >> 5, jg = u & 31;
    const int n0 = ng * 4, j0 = jg * 4;
    float acc[4][4];
    #pragma unroll
    for (int a = 0; a < 4; ++a)
      #pragma unroll
      for (int b = 0; b < 4; ++b) acc[a][b] = 0.f;
    #pragma unroll 8
    for (int c = 0; c < 32; ++c) {
      float4 zv = *(const float4*)&S[OFF_ZT + c * ZTP + n0];
      float4 wv = *(const float4*)(aW1 + c * 128 + j0);
      acc[0][0] += zv.x * wv.x; acc[0][1] += zv.x * wv.y; acc[0][2] += zv.x * wv.z; acc[0][3] += zv.x * wv.w;
      acc[1][0] += zv.y * wv.x; acc[1][1] += zv.y * wv.y; acc[1][2] += zv.y * wv.z; acc[1][3] += zv.y * wv.w;
      acc[2][0] += zv.z * wv.x; acc[2][1] += zv.z * wv.y; acc[2][2] += zv.z * wv.z; acc[2][3] += zv.z * wv.w;
      acc[3][0] += zv.w * wv.x; acc[3][1] += zv.w * wv.y; acc[3][2] += zv.w * wv.z; acc[3][3] += zv.w * wv.w;
    }
    float4 bv = *(const float4*)(ab1 + j0);
    float bj[4] = {bv.x, bv.y, bv.z, bv.w};
    #pragma unroll
    for (int b = 0; b < 4; ++b) {
      float4 hv;
      hv.x = fmaxf(acc[0][b] + bj[b], 0.f);
      hv.y = fmaxf(acc[1][b] + bj[b], 0.f);
      hv.z = fmaxf(acc[2][b] + bj[b], 0.f);
      hv.w = fmaxf(acc[3][b] + bj[b], 0.f);
      *(float4*)&S[OFF_HT + (j0 + b) * ZTP + n0] = hv;
    }
  }
  __syncthreads();

  // ---------- atom-out: thread = (n, kpair) ----------
  if (tid < 200) {
    const int n = tid / 5, kp = tid - (tid / 5) * 5, k0 = kp * 2;
    float a0 = ab2[k0] + abs_[k0];
    float a1 = ab2[k0 + 1] + abs_[k0 + 1];
    #pragma unroll 8
    for (int c = 0; c < 32; ++c) {
      float zc = S[OFF_ZT + c * ZTP + n];
      float2 w = *(const float2*)(aWs + c * 10 + k0);
      a0 += zc * w.x; a1 += zc * w.y;
    }
    #pragma unroll 8
    for (int j = 0; j < 128; ++j) {
      float hv = S[OFF_HT + j * ZTP + n];
      float2 w = *(const float2*)(aW2 + j * 10 + k0);
      a0 += hv * w.x; a1 += hv * w.y;
    }
    atom_out[(size_t)m * 400 + n * 10 + k0]     = a0;
    atom_out[(size_t)m * 400 + n * 10 + k0 + 1] = a1;
  }
  __syncthreads();   // hT dead; region A becomes Wsym

  // ---------- Wsym staging (symmetrized) ----------
  for (int e = tid; e < 5120; e += 256) {
    int t = e >> 10, r = e & 1023, c = r >> 5, d = r & 31;
    S[OFF_WS + t * WSP + c * WSR + d] =
        0.5f * (bond[t * 1024 + c * 32 + d] + bond[t * 1024 + d * 32 + c]);
  }
  __syncthreads();

  // ---------- U-phase: 4d x 4i tiles -> Ut[t][d][i] ----------
  // 400 units: t in [0,5), dg in [0,8), ig in [0,10)
  for (int u = tid; u < 400; u += 256) {
    const int t = u / 80, r = u - t * 80;
    const int dg = r / 10, ig = r - dg * 10;
    const int d0 = dg * 4, i0 = ig * 4;
    float acc[4][4];   // [di][ii]
    #pragma unroll
    for (int a = 0; a < 4; ++a)
      #pragma unroll
      for (int b = 0; b < 4; ++b) acc[a][b] = 0.f;
    #pragma unroll 8
    for (int c = 0; c < 32; ++c) {
      float4 zv = *(const float4*)&S[OFF_ZT + c * ZTP + i0];
      float4 wv = *(const float4*)&S[OFF_WS + t * WSP + c * WSR + d0];
      acc[0][0] += wv.x * zv.x; acc[0][1] += wv.x * zv.y; acc[0][2] += wv.x * zv.z; acc[0][3] += wv.x * zv.w;
      acc[1][0] += wv.y * zv.x; acc[1][1] += wv.y * zv.y; acc[1][2] += wv.y * zv.z; acc[1][3] += wv.y * zv.w;
      acc[2][0] += wv.z * zv.x; acc[2][1] += wv.z * zv.y; acc[2][2] += wv.z * zv.z; acc[2][3] += wv.z * zv.w;
      acc[3][0] += wv.w * zv.x; acc[3][1] += wv.w * zv.y; acc[3][2] += wv.w * zv.z; acc[3][3] += wv.w * zv.w;
    }
    #pragma unroll
    for (int a = 0; a < 4; ++a)
      *(float4*)&S[OFF_UT + t * UTP + (d0 + a) * ZTP + i0] =
          make_float4(acc[a][0], acc[a][1], acc[a][2], acc[a][3]);
  }
  __syncthreads();   // Wsym dead; bilT + hw alias into it (Ut preserved)

  // ---------- bilinear: 8i x 4j tiles -> bilT[t][p]; hw staged by idle threads ----------
  if (tid < 150) {
    const int t = tid / 30, q = tid - t * 30;
    int ig, jg;
    if (q < 10)      { ig = 0; jg = q; }
    else if (q < 18) { ig = 1; jg = q - 8; }
    else if (q < 24) { ig = 2; jg = q - 14; }
    else if (q < 28) { ig = 3; jg = q - 18; }
    else             { ig = 4; jg = q - 20; }
    const int i0 = ig * 8, j0 = jg * 4;
    float acc[8][4];
    #pragma unroll
    for (int a = 0; a < 8; ++a)
      #pragma unroll
      for (int b = 0; b < 4; ++b) acc[a][b] = 0.f;
    #pragma unroll 4
    for (int d = 0; d < 32; ++d) {
      float4 u0 = *(const float4*)&S[OFF_UT + t * UTP + d * ZTP + i0];
      float4 u1 = *(const float4*)&S[OFF_UT + t * UTP + d * ZTP + i0 + 4];
      float4 zv = *(const float4*)&S[OFF_ZT + d * ZTP + j0];
      float ua[8] = {u0.x,u0.y,u0.z,u0.w,u1.x,u1.y,u1.z,u1.w};
      #pragma unroll
      for (int a = 0; a < 8; ++a) {
        acc[a][0] += ua[a] * zv.x; acc[a][1] += ua[a] * zv.y;
        acc[a][2] += ua[a] * zv.z; acc[a][3] += ua[a] * zv.w;
      }
    }
    #pragma unroll
    for (int a = 0; a < 8; ++a) {
      const int i = i0 + a;
      #pragma unroll
      for (int b = 0; b < 4; ++b) {
        const int j = j0 + b;
        if (i < j) {
          const int p = i * (79 - i) / 2 + (j - i - 1);
          S[OFF_BT + t * 784 + p] = acc[a][b];
        }
      }
    }
  } else {
    // hw: w1h[320]@0, b1h[64]@320, w2t[320]@384, b2h[5]@704, wsh[25]@709, bsh[5]@734
    for (int idx = tid - 150; idx < 744; idx += 106) {
      float v;
      if (idx < 320) v = bW1[idx];
      else if (idx < 384) v = bb1[idx - 320];
      else if (idx < 704) { int qq = idx - 384; int t2 = qq >> 6, j = qq & 63; v = bW2[j * 5 + t2];
                            S[OFF_HW + 384 + t2 * 64 + j] = v; continue; }
      else if (idx < 709) v = bb2[idx - 704];
      else if (idx < 734) v = bWs[idx - 709];
      else v = bbs[idx - 734];
      S[OFF_HW + idx] = v;
    }
  }
  __syncthreads();

  // ---------- edge head: 4 pair-slots per thread ----------
  const float* w1h = &S[OFF_HW];
  const float* b1h = &S[OFF_HW + 320];
  const float* w2t = &S[OFF_HW + 384];
  const float* b2h = &S[OFF_HW + 704];
  const float* wsh = &S[OFF_HW + 709];
  const float* bsh = &S[OFF_HW + 734];

  float bil5[4][5], lg[4][5];
  #pragma unroll
  for (int s = 0; s < 4; ++s) {
    const int p = tid + (s << 8);
    const int pc = (p < NPAIR) ? p : 0;
    #pragma unroll
    for (int t = 0; t < 5; ++t) bil5[s][t] = S[OFF_BT + t * 784 + pc];
    #pragma unroll
    for (int t2 = 0; t2 < 5; ++t2) {
      float a = b2h[t2] + bsh[t2];
      #pragma unroll
      for (int t = 0; t < 5; ++t) a += bil5[s][t] * wsh[t * 5 + t2];
      lg[s][t2] = a;
    }
  }
  for (int j4 = 0; j4 < 16; ++j4) {
    float4 bb = ((const float4*)b1h)[j4];
    float4 w1v[5], w2v[5];
    #pragma unroll
    for (int t = 0; t < 5; ++t) {
      w1v[t] = ((const float4*)(w1h + t * 64))[j4];
      w2v[t] = ((const float4*)(w2t + t * 64))[j4];
    }
    #pragma unroll
    for (int s = 0; s < 4; ++s) {
      float4 h = bb;
      #pragma unroll
      for (int t = 0; t < 5; ++t) {
        float bt = bil5[s][t];
        h.x += bt * w1v[t].x; h.y += bt * w1v[t].y; h.z += bt * w1v[t].z; h.w += bt * w1v[t].w;
      }
      h.x = fmaxf(h.x, 0.f); h.y = fmaxf(h.y, 0.f); h.z = fmaxf(h.z, 0.f); h.w = fmaxf(h.w, 0.f);
      #pragma unroll
      for (int t2 = 0; t2 < 5; ++t2)
        lg[s][t2] += h.x * w2v[t2].x + h.y * w2v[t2].y + h.z * w2v[t2].z + h.w * w2v[t2].w;
    }
  }
  #pragma unroll
  for (int s = 0; s < 4; ++s) {
    const int p = tid + (s << 8);
    if (p >= NPAIR) continue;
    float mx = lg[s][0];
    #pragma unroll
    for (int t2 = 1; t2 < 5; ++t2) mx = fmaxf(mx, lg[s][t2]);
    float e[5], sum = 0.f;
    #pragma unroll
    for (int t2 = 0; t2 < 5; ++t2) { e[t2] = __expf(lg[s][t2] - mx); sum += e[t2]; }
    float inv = 1.f / sum;
    float* outp = edge_out + ((size_t)m * NPAIR + p) * 5;
    #pragma unroll
    for (int t2 = 0; t2 < 5; ++t2) outp[t2] = e[t2] * inv;
  }
}

extern "C" void kernel_launch(void* const* d_in, const int* in_sizes, int n_in,
                              void* d_out, int out_size, void* d_ws, size_t ws_size,
                              hipStream_t stream) {
  const float* eta    = (const float*)d_in[0];
  const float* gumbel = (const float*)d_in[1];
  const float* z_noise= (const float*)d_in[2];
  const float* cW1 = (const float*)d_in[3];
  const float* cb1 = (const float*)d_in[4];
  const float* cW2 = (const float*)d_in[5];
  const float* cb2 = (const float*)d_in[6];
  const float* cWs = (const float*)d_in[7];
  const float* cbs = (const float*)d_in[8];
  const float* means = (const float*)d_in[9];
  const float* lsig  = (const float*)d_in[10];
  const float* aW1 = (const float*)d_in[11];
  const float* ab1 = (const float*)d_in[12];
  const float* aW2 = (const float*)d_in[13];
  const float* ab2 = (const float*)d_in[14];
  const float* aWs = (const float*)d_in[15];
  const float* abs_= (const float*)d_in[16];
  const float* bond= (const float*)d_in[17];
  const float* bW1 = (const float*)d_in[18];
  const float* bb1 = (const float*)d_in[19];
  const float* bW2 = (const float*)d_in[20];
  const float* bb2 = (const float*)d_in[21];
  const float* bWs = (const float*)d_in[22];
  const float* bbs = (const float*)d_in[23];

  float* atom_out = (float*)d_out;                    // 1024*400
  float* edge_out = atom_out + (size_t)1024 * 400;    // 1024*780*5

  fused_kernel<<<1024, 256, 0, stream>>>(eta, gumbel, z_noise,
                                         cW1, cb1, cW2, cb2, cWs, cbs,
                                         means, lsig, aW1, ab1, aW2, ab2, aWs, abs_,
                                         bond, bW1, bb1, bW2, bb2, bWs, bbs,
                                         atom_out, edge_out);
}

// Round 6
// 195.537 us; speedup vs baseline: 1.2248x; 1.0795x over previous
//
#include <hip/hip_runtime.h>

constexpr int NPAIR = 780;

// ---- LDS layout (floats) ----
constexpr int ZTP    = 40;                 // Zt row stride
constexpr int OFF_ZT = 0;                  // Zt[32][40]               1280
constexpr int OFF_A  = 1280;               // aliased: hT[128][44]=5632 OR Ut[3][32][40]=3840
constexpr int OFF_HT = OFF_A;
constexpr int OFF_UT = OFF_A;
constexpr int UTP    = 1280;               // Ut plane stride
constexpr int OFF_BT = OFF_A + 3840;       // bilT[5][780] = 3900   (hT tail overlaps here; dead by then)
constexpr int OFF_HW = OFF_BT + 3900;      // head weights 744  @9020
constexpr int OFF_ET = OFF_HW + 744;       // etas[64]   @9764
constexpr int OFF_HC = OFF_ET + 64;        // hcl[128]   @9828
constexpr int OFF_LP = OFF_HC + 128;       // lps[32]    @9956
constexpr int SH_TOT = OFF_LP + 32;        // 9988 fl = 39952 B -> 4 blocks/CU

// =================== prep: symmetrize bond + sigma table ===================
__global__ __launch_bounds__(256) void prep_kernel(
    const float* __restrict__ bond, const float* __restrict__ lsig,
    float* __restrict__ wsym, float* __restrict__ sigma)
{
  const int e = blockIdx.x * 256 + threadIdx.x;
  if (e < 5120) {
    const int t = e >> 10, r = e & 1023, c = r >> 5, d = r & 31;
    wsym[e] = 0.5f * (bond[e] + bond[t * 1024 + d * 32 + c]);
  } else if (e < 6144) {
    const int q = e - 5120;
    sigma[q] = __expf(fminf(fmaxf(lsig[q], -20.f), 30.f));
  }
}

// =================== fused per-molecule kernel ===================
__global__ __launch_bounds__(256, 4) void fused_kernel(
    const float* __restrict__ eta, const float* __restrict__ gumbel,
    const float* __restrict__ z_noise,
    const float* __restrict__ cW1, const float* __restrict__ cb1,
    const float* __restrict__ cW2, const float* __restrict__ cb2,
    const float* __restrict__ cWs, const float* __restrict__ cbs,
    const float* __restrict__ means, const float* __restrict__ sigma,
    const float* __restrict__ aW1, const float* __restrict__ ab1,
    const float* __restrict__ aW2, const float* __restrict__ ab2,
    const float* __restrict__ aWs, const float* __restrict__ abs_,
    const float* __restrict__ wsym,
    const float* __restrict__ bW1, const float* __restrict__ bb1,
    const float* __restrict__ bW2, const float* __restrict__ bb2,
    const float* __restrict__ bWs, const float* __restrict__ bbs,
    float* __restrict__ atom_out, float* __restrict__ edge_out)
{
  __shared__ __align__(16) float S[SH_TOT];
  const int tid = threadIdx.x;
  const int m = blockIdx.x;

  // ---------- phase 1: eta ----------
  if (tid < 64) S[OFF_ET + tid] = eta[m * 64 + tid];
  __syncthreads();

  // ---------- phase 2: cluster h (tid<128) ; head-weight staging (tid>=128) ----------
  if (tid < 128) {
    float h = cb1[tid];
    #pragma unroll 8
    for (int d = 0; d < 64; ++d) h += S[OFF_ET + d] * cW1[d * 128 + tid];
    S[OFF_HC + tid] = fmaxf(h, 0.f);
  } else {
    // hw: w1h[320]@0, b1h[64]@320, w2t[320]@384 (bW2^T), b2h[5]@704, wsh[25]@709, bsh[5]@734
    for (int idx = tid - 128; idx < 739; idx += 128) {
      float v;
      if (idx < 320) v = bW1[idx];
      else if (idx < 384) v = bb1[idx - 320];
      else if (idx < 704) { int qq = idx - 384; int t2 = qq >> 6, j = qq & 63;
                            S[OFF_HW + 384 + t2 * 64 + j] = bW2[j * 5 + t2]; continue; }
      else if (idx < 709) v = bb2[idx - 704];
      else if (idx < 734) v = bWs[idx - 709];
      else v = bbs[idx - 734];
      S[OFF_HW + idx] = v;
    }
  }
  __syncthreads();

  // ---------- phase 3: cluster logits + log-softmax ----------
  if (tid < 32) {
    float x = cb2[tid] + cbs[tid];
    #pragma unroll 8
    for (int j = 0; j < 128; ++j) x += S[OFF_HC + j] * cW2[j * 32 + tid];
    #pragma unroll 8
    for (int d = 0; d < 64; ++d)  x += S[OFF_ET + d] * cWs[d * 32 + tid];
    float mx = x;
    for (int off = 16; off; off >>= 1) mx = fmaxf(mx, __shfl_xor(mx, off));
    float e = __expf(x - mx);
    float s = e;
    for (int off = 16; off; off >>= 1) s += __shfl_xor(s, off);
    S[OFF_LP + tid] = (x - mx) - __logf(s);
  }
  __syncthreads();

  // ---------- phase 4: z sample -> Zt[c][n] ----------
  if (tid < 40) {
    const int n = m * 40 + tid;
    float g[32];
    const float4* g4 = (const float4*)(gumbel + (size_t)n * 32);
    #pragma unroll
    for (int q = 0; q < 8; ++q) {
      float4 v = g4[q];
      g[4*q] = v.x; g[4*q+1] = v.y; g[4*q+2] = v.z; g[4*q+3] = v.w;
    }
    int kb = 0; float vb = S[OFF_LP] + g[0];
    #pragma unroll
    for (int c = 1; c < 32; ++c) {
      float v = S[OFF_LP + c] + g[c];
      if (v > vb) { vb = v; kb = c; }   // first-index tie-break
    }
    const float4* zn4 = (const float4*)(z_noise + (size_t)n * 32);
    const float4* mk4 = (const float4*)(means + kb * 32);
    const float4* sg4 = (const float4*)(sigma + kb * 32);
    #pragma unroll
    for (int q = 0; q < 8; ++q) {
      float4 zn = zn4[q], mk = mk4[q], sg = sg4[q];
      S[OFF_ZT + (4*q    ) * ZTP + tid] = zn.x * sg.x + mk.x;
      S[OFF_ZT + (4*q + 1) * ZTP + tid] = zn.y * sg.y + mk.y;
      S[OFF_ZT + (4*q + 2) * ZTP + tid] = zn.z * sg.z + mk.z;
      S[OFF_ZT + (4*q + 3) * ZTP + tid] = zn.w * sg.w + mk.w;
    }
  }
  __syncthreads();

  // ---------- phase 5: atom-h, 4n x 4j tiles -> hT[j][n] (stride 44) ----------
  for (int u = tid; u < 320; u += 256) {
    const int ng = u >> 5, jg = u & 31;
    const int n0 = ng * 4, j0 = jg * 4;
    float acc[4][4];
    #pragma unroll
    for (int a = 0; a < 4; ++a)
      #pragma unroll
      for (int b = 0; b < 4; ++b) acc[a][b] = 0.f;
    #pragma unroll 8
    for (int c = 0; c < 32; ++c) {
      float4 zv = *(const float4*)&S[OFF_ZT + c * ZTP + n0];
      float4 wv = *(const float4*)(aW1 + c * 128 + j0);
      acc[0][0] += zv.x * wv.x; acc[0][1] += zv.x * wv.y; acc[0][2] += zv.x * wv.z; acc[0][3] += zv.x * wv.w;
      acc[1][0] += zv.y * wv.x; acc[1][1] += zv.y * wv.y; acc[1][2] += zv.y * wv.z; acc[1][3] += zv.y * wv.w;
      acc[2][0] += zv.z * wv.x; acc[2][1] += zv.z * wv.y; acc[2][2] += zv.z * wv.z; acc[2][3] += zv.z * wv.w;
      acc[3][0] += zv.w * wv.x; acc[3][1] += zv.w * wv.y; acc[3][2] += zv.w * wv.z; acc[3][3] += zv.w * wv.w;
    }
    float4 bv = *(const float4*)(ab1 + j0);
    float bj[4] = {bv.x, bv.y, bv.z, bv.w};
    #pragma unroll
    for (int b = 0; b < 4; ++b) {
      float4 hv;
      hv.x = fmaxf(acc[0][b] + bj[b], 0.f);
      hv.y = fmaxf(acc[1][b] + bj[b], 0.f);
      hv.z = fmaxf(acc[2][b] + bj[b], 0.f);
      hv.w = fmaxf(acc[3][b] + bj[b], 0.f);
      *(float4*)&S[OFF_HT + (j0 + b) * 44 + n0] = hv;
    }
  }
  __syncthreads();

  // ---------- phase 6: atom-out, thread = (n, kpair) ----------
  if (tid < 200) {
    const int n = tid / 5, kp = tid - (tid / 5) * 5, k0 = kp * 2;
    float a0 = ab2[k0] + abs_[k0];
    float a1 = ab2[k0 + 1] + abs_[k0 + 1];
    #pragma unroll 8
    for (int c = 0; c < 32; ++c) {
      float zc = S[OFF_ZT + c * ZTP + n];
      float2 w = *(const float2*)(aWs + c * 10 + k0);
      a0 += zc * w.x; a1 += zc * w.y;
    }
    #pragma unroll 8
    for (int j = 0; j < 128; ++j) {
      float hv = S[OFF_HT + j * 44 + n];
      float2 w = *(const float2*)(aW2 + j * 10 + k0);
      a0 += hv * w.x; a1 += hv * w.y;
    }
    *(float2*)(atom_out + (size_t)m * 400 + n * 10 + k0) = make_float2(a0, a1);
  }
  __syncthreads();   // hT dead

  // ---------- phases 7-10: U + bilinear in two t-rounds ----------
  #pragma unroll
  for (int R = 0; R < 2; ++R) {
    const int tbase = (R == 0) ? 0 : 3;
    const int nplanes = (R == 0) ? 3 : 2;
    // U: units (tloc, dg, ig) -> Ut[tloc][d][i]
    for (int u = tid; u < nplanes * 80; u += 256) {
      const int tl = u / 80, r = u - tl * 80;
      const int dg = r / 10, ig = r - dg * 10;
      const int d0 = dg * 4, i0 = ig * 4;
      const float* wg = wsym + (tbase + tl) * 1024;
      float acc[4][4];   // [di][ii]
      #pragma unroll
      for (int a = 0; a < 4; ++a)
        #pragma unroll
        for (int b = 0; b < 4; ++b) acc[a][b] = 0.f;
      #pragma unroll 8
      for (int c = 0; c < 32; ++c) {
        float4 zv = *(const float4*)&S[OFF_ZT + c * ZTP + i0];
        float4 wv = *(const float4*)(wg + c * 32 + d0);
        acc[0][0] += wv.x * zv.x; acc[0][1] += wv.x * zv.y; acc[0][2] += wv.x * zv.z; acc[0][3] += wv.x * zv.w;
        acc[1][0] += wv.y * zv.x; acc[1][1] += wv.y * zv.y; acc[1][2] += wv.y * zv.z; acc[1][3] += wv.y * zv.w;
        acc[2][0] += wv.z * zv.x; acc[2][1] += wv.z * zv.y; acc[2][2] += wv.z * zv.z; acc[2][3] += wv.z * zv.w;
        acc[3][0] += wv.w * zv.x; acc[3][1] += wv.w * zv.y; acc[3][2] += wv.w * zv.z; acc[3][3] += wv.w * zv.w;
      }
      #pragma unroll
      for (int a = 0; a < 4; ++a)
        *(float4*)&S[OFF_UT + tl * UTP + (d0 + a) * ZTP + i0] =
            make_float4(acc[a][0], acc[a][1], acc[a][2], acc[a][3]);
    }
    __syncthreads();

    // bilinear: units (tloc, q) with 8i x 4j tiles -> bilT[t][p]
    if (tid < nplanes * 30) {
      const int tl = tid / 30, q = tid - tl * 30;
      const int tg = tbase + tl;
      int ig, jg;
      if (q < 10)      { ig = 0; jg = q; }
      else if (q < 18) { ig = 1; jg = q - 8; }
      else if (q < 24) { ig = 2; jg = q - 14; }
      else if (q < 28) { ig = 3; jg = q - 18; }
      else             { ig = 4; jg = q - 20; }
      const int i0 = ig * 8, j0 = jg * 4;
      float acc[8][4];
      #pragma unroll
      for (int a = 0; a < 8; ++a)
        #pragma unroll
        for (int b = 0; b < 4; ++b) acc[a][b] = 0.f;
      #pragma unroll 4
      for (int d = 0; d < 32; ++d) {
        float4 u0 = *(const float4*)&S[OFF_UT + tl * UTP + d * ZTP + i0];
        float4 u1 = *(const float4*)&S[OFF_UT + tl * UTP + d * ZTP + i0 + 4];
        float4 zv = *(const float4*)&S[OFF_ZT + d * ZTP + j0];
        float ua[8] = {u0.x,u0.y,u0.z,u0.w,u1.x,u1.y,u1.z,u1.w};
        #pragma unroll
        for (int a = 0; a < 8; ++a) {
          acc[a][0] += ua[a] * zv.x; acc[a][1] += ua[a] * zv.y;
          acc[a][2] += ua[a] * zv.z; acc[a][3] += ua[a] * zv.w;
        }
      }
      #pragma unroll
      for (int a = 0; a < 8; ++a) {
        const int i = i0 + a;
        #pragma unroll
        for (int b = 0; b < 4; ++b) {
          const int j = j0 + b;
          if (i < j) {
            const int p = i * (79 - i) / 2 + (j - i - 1);
            S[OFF_BT + tg * 780 + p] = acc[a][b];
          }
        }
      }
    }
    __syncthreads();
  }

  // ---------- phase 11: edge head, 4 pair-slots per thread ----------
  const float* w1h = &S[OFF_HW];
  const float* b1h = &S[OFF_HW + 320];
  const float* w2t = &S[OFF_HW + 384];
  const float* b2h = &S[OFF_HW + 704];
  const float* wsh = &S[OFF_HW + 709];
  const float* bsh = &S[OFF_HW + 734];

  float bil5[4][5], lg[4][5];
  #pragma unroll
  for (int s = 0; s < 4; ++s) {
    const int p = tid + (s << 8);
    const int pc = (p < NPAIR) ? p : 0;
    #pragma unroll
    for (int t = 0; t < 5; ++t) bil5[s][t] = S[OFF_BT + t * 780 + pc];
    #pragma unroll
    for (int t2 = 0; t2 < 5; ++t2) {
      float a = b2h[t2] + bsh[t2];
      #pragma unroll
      for (int t = 0; t < 5; ++t) a += bil5[s][t] * wsh[t * 5 + t2];
      lg[s][t2] = a;
    }
  }
  for (int j4 = 0; j4 < 16; ++j4) {
    float4 bb = ((const float4*)b1h)[j4];
    float4 h[4];
    #pragma unroll
    for (int s = 0; s < 4; ++s) h[s] = bb;
    #pragma unroll
    for (int t = 0; t < 5; ++t) {
      float4 w1 = ((const float4*)(w1h + t * 64))[j4];
      #pragma unroll
      for (int s = 0; s < 4; ++s) {
        float bt = bil5[s][t];
        h[s].x += bt * w1.x; h[s].y += bt * w1.y; h[s].z += bt * w1.z; h[s].w += bt * w1.w;
      }
    }
    #pragma unroll
    for (int s = 0; s < 4; ++s) {
      h[s].x = fmaxf(h[s].x, 0.f); h[s].y = fmaxf(h[s].y, 0.f);
      h[s].z = fmaxf(h[s].z, 0.f); h[s].w = fmaxf(h[s].w, 0.f);
    }
    #pragma unroll
    for (int t2 = 0; t2 < 5; ++t2) {
      float4 w2 = ((const float4*)(w2t + t2 * 64))[j4];
      #pragma unroll
      for (int s = 0; s < 4; ++s)
        lg[s][t2] += h[s].x * w2.x + h[s].y * w2.y + h[s].z * w2.z + h[s].w * w2.w;
    }
  }
  #pragma unroll
  for (int s = 0; s < 4; ++s) {
    const int p = tid + (s << 8);
    if (p >= NPAIR) continue;
    float mx = lg[s][0];
    #pragma unroll
    for (int t2 = 1; t2 < 5; ++t2) mx = fmaxf(mx, lg[s][t2]);
    float e[5], sum = 0.f;
    #pragma unroll
    for (int t2 = 0; t2 < 5; ++t2) { e[t2] = __expf(lg[s][t2] - mx); sum += e[t2]; }
    float inv = 1.f / sum;
    float* outp = edge_out + ((size_t)m * NPAIR + p) * 5;
    #pragma unroll
    for (int t2 = 0; t2 < 5; ++t2) outp[t2] = e[t2] * inv;
  }
}

extern "C" void kernel_launch(void* const* d_in, const int* in_sizes, int n_in,
                              void* d_out, int out_size, void* d_ws, size_t ws_size,
                              hipStream_t stream) {
  const float* eta    = (const float*)d_in[0];
  const float* gumbel = (const float*)d_in[1];
  const float* z_noise= (const float*)d_in[2];
  const float* cW1 = (const float*)d_in[3];
  const float* cb1 = (const float*)d_in[4];
  const float* cW2 = (const float*)d_in[5];
  const float* cb2 = (const float*)d_in[6];
  const float* cWs = (const float*)d_in[7];
  const float* cbs = (const float*)d_in[8];
  const float* means = (const float*)d_in[9];
  const float* lsig  = (const float*)d_in[10];
  const float* aW1 = (const float*)d_in[11];
  const float* ab1 = (const float*)d_in[12];
  const float* aW2 = (const float*)d_in[13];
  const float* ab2 = (const float*)d_in[14];
  const float* aWs = (const float*)d_in[15];
  const float* abs_= (const float*)d_in[16];
  const float* bond= (const float*)d_in[17];
  const float* bW1 = (const float*)d_in[18];
  const float* bb1 = (const float*)d_in[19];
  const float* bW2 = (const float*)d_in[20];
  const float* bb2 = (const float*)d_in[21];
  const float* bWs = (const float*)d_in[22];
  const float* bbs = (const float*)d_in[23];

  float* wsym  = (float*)d_ws;       // 5120 fl
  float* sigma = wsym + 5120;        // 1024 fl
  float* atom_out = (float*)d_out;                    // 1024*400
  float* edge_out = atom_out + (size_t)1024 * 400;    // 1024*780*5

  prep_kernel<<<24, 256, 0, stream>>>(bond, lsig, wsym, sigma);
  fused_kernel<<<1024, 256, 0, stream>>>(eta, gumbel, z_noise,
                                         cW1, cb1, cW2, cb2, cWs, cbs,
                                         means, sigma, aW1, ab1, aW2, ab2, aWs, abs_,
                                         wsym, bW1, bb1, bW2, bb2, bWs, bbs,
                                         atom_out, edge_out);
}

// Round 7
// 189.916 us; speedup vs baseline: 1.2611x; 1.0296x over previous
//
#include <hip/hip_runtime.h>

constexpr int NPAIR = 780;

// ---- fused-kernel LDS layout (floats) ----
constexpr int OFF_ZT = 0;            // Zt[32][40] stride 40          1280
constexpr int OFF_A  = 1280;         // hT[128][44]=5632  |  Ut[3][32][40]=3840
constexpr int UTP    = 1280;         // Ut plane stride
constexpr int OFF_BT = 5120;         // bilT[5][780] = 3900  (ends 9020)
constexpr int OFF_HW = 9020;         // head weights 744     (ends 9764)
constexpr int SH_TOT = 9764;         // 39056 B -> 4 blocks/CU

// =================== prep: cluster head + wsym + sigma + head-weight table ===================
__global__ __launch_bounds__(256) void prep_kernel(
    const float* __restrict__ eta,
    const float* __restrict__ cW1, const float* __restrict__ cb1,
    const float* __restrict__ cW2, const float* __restrict__ cb2,
    const float* __restrict__ cWs, const float* __restrict__ cbs,
    const float* __restrict__ bond, const float* __restrict__ lsig,
    const float* __restrict__ bW1, const float* __restrict__ bb1,
    const float* __restrict__ bW2, const float* __restrict__ bb2,
    const float* __restrict__ bWs, const float* __restrict__ bbs,
    float* __restrict__ log_pi, float* __restrict__ wsym,
    float* __restrict__ sigma, float* __restrict__ hwg)
{
  if (blockIdx.x < 256) {
    // ---- cluster head: 4 rows per block (verified R2 kernel) ----
    const int lane = threadIdx.x & 63, wid = threadIdx.x >> 6;
    const int row = blockIdx.x * 4 + wid;
    __shared__ __align__(16) float etas[4][64];
    __shared__ __align__(16) float hs[4][128];
    etas[wid][lane] = eta[row * 64 + lane];
    __syncthreads();
    float a0 = cb1[lane], a1 = cb1[lane + 64];
    for (int d = 0; d < 64; ++d) {
      float ed = etas[wid][d];
      a0 += ed * cW1[d * 128 + lane];
      a1 += ed * cW1[d * 128 + lane + 64];
    }
    hs[wid][lane] = fmaxf(a0, 0.f);
    hs[wid][lane + 64] = fmaxf(a1, 0.f);
    __syncthreads();
    if (lane < 32) {
      float x = cb2[lane] + cbs[lane];
      for (int j = 0; j < 128; ++j) x += hs[wid][j] * cW2[j * 32 + lane];
      for (int d = 0; d < 64; ++d) x += etas[wid][d] * cWs[d * 32 + lane];
      float m = x;
      for (int off = 16; off; off >>= 1) m = fmaxf(m, __shfl_xor(m, off));
      float e = __expf(x - m);
      float s = e;
      for (int off = 16; off; off >>= 1) s += __shfl_xor(s, off);
      log_pi[row * 32 + lane] = (x - m) - __logf(s);
    }
  } else {
    const int e = (blockIdx.x - 256) * 256 + threadIdx.x;
    if (e < 5120) {
      const int t = e >> 10, r = e & 1023, c = r >> 5, d = r & 31;
      wsym[e] = 0.5f * (bond[e] + bond[t * 1024 + d * 32 + c]);
    } else if (e < 6144) {
      const int q = e - 5120;
      sigma[q] = __expf(fminf(fmaxf(lsig[q], -20.f), 30.f));
    } else if (e < 6888) {
      // hwg: w1h[320]@0, b1h[64]@320, w2t[320]@384 (bW2^T), b2h[5]@704, wsh[25]@709, bsh[5]@734
      const int idx = e - 6144;
      float v;
      if (idx < 320) v = bW1[idx];
      else if (idx < 384) v = bb1[idx - 320];
      else if (idx < 704) { int qq = idx - 384; int t2 = qq >> 6, j = qq & 63; v = bW2[j * 5 + t2]; }
      else if (idx < 709) v = bb2[idx - 704];
      else if (idx < 734) v = bWs[idx - 709];
      else v = bbs[idx - 734];
      hwg[idx] = v;
    }
  }
}

// =================== fused per-molecule kernel ===================
__global__ __launch_bounds__(256, 4) void fused_kernel(
    const float* __restrict__ log_pi, const float* __restrict__ gumbel,
    const float* __restrict__ z_noise,
    const float* __restrict__ means, const float* __restrict__ sigma,
    const float* __restrict__ aW1, const float* __restrict__ ab1,
    const float* __restrict__ aW2, const float* __restrict__ ab2,
    const float* __restrict__ aWs, const float* __restrict__ abs_,
    const float* __restrict__ wsym, const float* __restrict__ hwg,
    float* __restrict__ atom_out, float* __restrict__ edge_out)
{
  __shared__ __align__(16) float S[SH_TOT];
  const int tid = threadIdx.x;
  const int m = blockIdx.x;

  // ---------- phase 1: z sample (tid<40) + head-weight staging (tid>=64) ----------
  if (tid < 40) {
    const int n = m * 40 + tid;
    float lp[32];
    #pragma unroll
    for (int c = 0; c < 32; ++c) lp[c] = log_pi[m * 32 + c];   // uniform -> scalar loads
    float g[32];
    const float4* g4 = (const float4*)(gumbel + (size_t)n * 32);
    #pragma unroll
    for (int q = 0; q < 8; ++q) {
      float4 v = g4[q];
      g[4*q] = v.x; g[4*q+1] = v.y; g[4*q+2] = v.z; g[4*q+3] = v.w;
    }
    int kb = 0; float vb = lp[0] + g[0];
    #pragma unroll
    for (int c = 1; c < 32; ++c) {
      float v = lp[c] + g[c];
      if (v > vb) { vb = v; kb = c; }   // first-index tie-break
    }
    const float4* zn4 = (const float4*)(z_noise + (size_t)n * 32);
    const float4* mk4 = (const float4*)(means + kb * 32);
    const float4* sg4 = (const float4*)(sigma + kb * 32);
    #pragma unroll
    for (int q = 0; q < 8; ++q) {
      float4 zn = zn4[q], mk = mk4[q], sg = sg4[q];
      S[OFF_ZT + (4*q    ) * 40 + tid] = zn.x * sg.x + mk.x;
      S[OFF_ZT + (4*q + 1) * 40 + tid] = zn.y * sg.y + mk.y;
      S[OFF_ZT + (4*q + 2) * 40 + tid] = zn.z * sg.z + mk.z;
      S[OFF_ZT + (4*q + 3) * 40 + tid] = zn.w * sg.w + mk.w;
    }
  } else if (tid >= 64) {
    for (int idx = tid - 64; idx < 744; idx += 192) S[OFF_HW + idx] = hwg[idx];
  }
  __syncthreads();

  // ---------- phase 2: atom-h, 4n x 4j tiles -> hT[j][n] (stride 44) ----------
  for (int u = tid; u < 320; u += 256) {
    const int ng = u >> 5, jg = u & 31;
    const int n0 = ng * 4, j0 = jg * 4;
    float acc[4][4];
    #pragma unroll
    for (int a = 0; a < 4; ++a)
      #pragma unroll
      for (int b = 0; b < 4; ++b) acc[a][b] = 0.f;
    #pragma unroll 8
    for (int c = 0; c < 32; ++c) {
      float4 zv = *(const float4*)&S[OFF_ZT + c * 40 + n0];
      float4 wv = *(const float4*)(aW1 + c * 128 + j0);
      acc[0][0] += zv.x * wv.x; acc[0][1] += zv.x * wv.y; acc[0][2] += zv.x * wv.z; acc[0][3] += zv.x * wv.w;
      acc[1][0] += zv.y * wv.x; acc[1][1] += zv.y * wv.y; acc[1][2] += zv.y * wv.z; acc[1][3] += zv.y * wv.w;
      acc[2][0] += zv.z * wv.x; acc[2][1] += zv.z * wv.y; acc[2][2] += zv.z * wv.z; acc[2][3] += zv.z * wv.w;
      acc[3][0] += zv.w * wv.x; acc[3][1] += zv.w * wv.y; acc[3][2] += zv.w * wv.z; acc[3][3] += zv.w * wv.w;
    }
    float4 bv = *(const float4*)(ab1 + j0);
    float bj[4] = {bv.x, bv.y, bv.z, bv.w};
    #pragma unroll
    for (int b = 0; b < 4; ++b) {
      float4 hv;
      hv.x = fmaxf(acc[0][b] + bj[b], 0.f);
      hv.y = fmaxf(acc[1][b] + bj[b], 0.f);
      hv.z = fmaxf(acc[2][b] + bj[b], 0.f);
      hv.w = fmaxf(acc[3][b] + bj[b], 0.f);
      *(float4*)&S[OFF_A + (j0 + b) * 44 + n0] = hv;
    }
  }
  __syncthreads();

  // ---------- phase 3: atom-out, thread = (n, kpair) ----------
  if (tid < 200) {
    const int n = tid / 5, kp = tid - (tid / 5) * 5, k0 = kp * 2;
    float a0 = ab2[k0] + abs_[k0];
    float a1 = ab2[k0 + 1] + abs_[k0 + 1];
    #pragma unroll 8
    for (int c = 0; c < 32; ++c) {
      float zc = S[OFF_ZT + c * 40 + n];
      float2 w = *(const float2*)(aWs + c * 10 + k0);
      a0 += zc * w.x; a1 += zc * w.y;
    }
    #pragma unroll 8
    for (int j = 0; j < 128; ++j) {
      float hv = S[OFF_A + j * 44 + n];
      float2 w = *(const float2*)(aW2 + j * 10 + k0);
      a0 += hv * w.x; a1 += hv * w.y;
    }
    *(float2*)(atom_out + (size_t)m * 400 + n * 10 + k0) = make_float2(a0, a1);
  }
  __syncthreads();   // hT dead

  // ---------- phases 4-5: U + bilinear, two t-rounds ----------
  #pragma unroll
  for (int R = 0; R < 2; ++R) {
    const int tbase = (R == 0) ? 0 : 3;
    const int nplanes = (R == 0) ? 3 : 2;
    // U: units (tl, dg, ig) -> Ut[tl][d][i]
    for (int u = tid; u < nplanes * 80; u += 256) {
      const int tl = u / 80, r = u - tl * 80;
      const int dg = r / 10, ig = r - dg * 10;
      const int d0 = dg * 4, i0 = ig * 4;
      const float* wg = wsym + (tbase + tl) * 1024;
      float acc[4][4];   // [di][ii]
      #pragma unroll
      for (int a = 0; a < 4; ++a)
        #pragma unroll
        for (int b = 0; b < 4; ++b) acc[a][b] = 0.f;
      #pragma unroll 8
      for (int c = 0; c < 32; ++c) {
        float4 zv = *(const float4*)&S[OFF_ZT + c * 40 + i0];
        float4 wv = *(const float4*)(wg + c * 32 + d0);
        acc[0][0] += wv.x * zv.x; acc[0][1] += wv.x * zv.y; acc[0][2] += wv.x * zv.z; acc[0][3] += wv.x * zv.w;
        acc[1][0] += wv.y * zv.x; acc[1][1] += wv.y * zv.y; acc[1][2] += wv.y * zv.z; acc[1][3] += wv.y * zv.w;
        acc[2][0] += wv.z * zv.x; acc[2][1] += wv.z * zv.y; acc[2][2] += wv.z * zv.z; acc[2][3] += wv.z * zv.w;
        acc[3][0] += wv.w * zv.x; acc[3][1] += wv.w * zv.y; acc[3][2] += wv.w * zv.z; acc[3][3] += wv.w * zv.w;
      }
      #pragma unroll
      for (int a = 0; a < 4; ++a)
        *(float4*)&S[OFF_A + tl * UTP + (d0 + a) * 40 + i0] =
            make_float4(acc[a][0], acc[a][1], acc[a][2], acc[a][3]);
    }
    __syncthreads();

    // bilinear: units (tl, triangular 4i x 4j tile); 165 / 110 units
    if (tid < nplanes * 55) {
      const int tl = tid / 55;
      int q = tid - tl * 55;
      int ig = 0;
      while (q >= 10 - ig) { q -= 10 - ig; ++ig; }
      const int jg = ig + q;
      const int i0 = ig * 4, j0 = jg * 4;
      float acc[4][4];
      #pragma unroll
      for (int a = 0; a < 4; ++a)
        #pragma unroll
        for (int b = 0; b < 4; ++b) acc[a][b] = 0.f;
      #pragma unroll 8
      for (int d = 0; d < 32; ++d) {
        float4 uv = *(const float4*)&S[OFF_A + tl * UTP + d * 40 + i0];
        float4 zv = *(const float4*)&S[OFF_ZT + d * 40 + j0];
        acc[0][0] += uv.x * zv.x; acc[0][1] += uv.x * zv.y; acc[0][2] += uv.x * zv.z; acc[0][3] += uv.x * zv.w;
        acc[1][0] += uv.y * zv.x; acc[1][1] += uv.y * zv.y; acc[1][2] += uv.y * zv.z; acc[1][3] += uv.y * zv.w;
        acc[2][0] += uv.z * zv.x; acc[2][1] += uv.z * zv.y; acc[2][2] += uv.z * zv.z; acc[2][3] += uv.z * zv.w;
        acc[3][0] += uv.w * zv.x; acc[3][1] += uv.w * zv.y; acc[3][2] += uv.w * zv.z; acc[3][3] += uv.w * zv.w;
      }
      const int tg = tbase + tl;
      #pragma unroll
      for (int a = 0; a < 4; ++a) {
        const int i = i0 + a;
        #pragma unroll
        for (int b = 0; b < 4; ++b) {
          const int j = j0 + b;
          if (i < j) {
            const int p = i * (79 - i) / 2 + (j - i - 1);
            S[OFF_BT + tg * 780 + p] = acc[a][b];
          }
        }
      }
    }
    __syncthreads();
  }

  // ---------- phase 6: edge head ----------
  const float* w1h = &S[OFF_HW];
  const float* b1h = &S[OFF_HW + 320];
  const float* w2t = &S[OFF_HW + 384];
  const float* b2h = &S[OFF_HW + 704];
  const float* wsh = &S[OFF_HW + 709];
  const float* bsh = &S[OFF_HW + 734];

  // main: 3 unconditional slots (pairs 0..767)
  float bil5[3][5], lg[3][5];
  #pragma unroll
  for (int s = 0; s < 3; ++s) {
    const int p = tid + (s << 8);
    #pragma unroll
    for (int t = 0; t < 5; ++t) bil5[s][t] = S[OFF_BT + t * 780 + p];
    #pragma unroll
    for (int t2 = 0; t2 < 5; ++t2) {
      float a = b2h[t2] + bsh[t2];
      #pragma unroll
      for (int t = 0; t < 5; ++t) a += bil5[s][t] * wsh[t * 5 + t2];
      lg[s][t2] = a;
    }
  }
  for (int j4 = 0; j4 < 16; ++j4) {
    float4 bb = ((const float4*)b1h)[j4];
    float4 h[3];
    #pragma unroll
    for (int s = 0; s < 3; ++s) h[s] = bb;
    #pragma unroll
    for (int t = 0; t < 5; ++t) {
      float4 w1 = ((const float4*)(w1h + t * 64))[j4];
      #pragma unroll
      for (int s = 0; s < 3; ++s) {
        float bt = bil5[s][t];
        h[s].x += bt * w1.x; h[s].y += bt * w1.y; h[s].z += bt * w1.z; h[s].w += bt * w1.w;
      }
    }
    #pragma unroll
    for (int s = 0; s < 3; ++s) {
      h[s].x = fmaxf(h[s].x, 0.f); h[s].y = fmaxf(h[s].y, 0.f);
      h[s].z = fmaxf(h[s].z, 0.f); h[s].w = fmaxf(h[s].w, 0.f);
    }
    #pragma unroll
    for (int t2 = 0; t2 < 5; ++t2) {
      float4 w2 = ((const float4*)(w2t + t2 * 64))[j4];
      #pragma unroll
      for (int s = 0; s < 3; ++s)
        lg[s][t2] += h[s].x * w2.x + h[s].y * w2.y + h[s].z * w2.z + h[s].w * w2.w;
    }
  }
  #pragma unroll
  for (int s = 0; s < 3; ++s) {
    const int p = tid + (s << 8);
    float mx = lg[s][0];
    #pragma unroll
    for (int t2 = 1; t2 < 5; ++t2) mx = fmaxf(mx, lg[s][t2]);
    float e[5], sum = 0.f;
    #pragma unroll
    for (int t2 = 0; t2 < 5; ++t2) { e[t2] = __expf(lg[s][t2] - mx); sum += e[t2]; }
    float inv = 1.f / sum;
    float* outp = edge_out + ((size_t)m * NPAIR + p) * 5;
    #pragma unroll
    for (int t2 = 0; t2 < 5; ++t2) outp[t2] = e[t2] * inv;
  }

  // tail: pairs 768..779 on wave 0
  if (tid < 12) {
    const int p = 768 + tid;
    float bt[5], lgt[5];
    #pragma unroll
    for (int t = 0; t < 5; ++t) bt[t] = S[OFF_BT + t * 780 + p];
    #pragma unroll
    for (int t2 = 0; t2 < 5; ++t2) {
      float a = b2h[t2] + bsh[t2];
      #pragma unroll
      for (int t = 0; t < 5; ++t) a += bt[t] * wsh[t * 5 + t2];
      lgt[t2] = a;
    }
    for (int j = 0; j < 64; ++j) {
      float hv = b1h[j];
      #pragma unroll
      for (int t = 0; t < 5; ++t) hv += bt[t] * w1h[t * 64 + j];
      hv = fmaxf(hv, 0.f);
      #pragma unroll
      for (int t2 = 0; t2 < 5; ++t2) lgt[t2] += hv * w2t[t2 * 64 + j];
    }
    float mx = lgt[0];
    #pragma unroll
    for (int t2 = 1; t2 < 5; ++t2) mx = fmaxf(mx, lgt[t2]);
    float e[5], sum = 0.f;
    #pragma unroll
    for (int t2 = 0; t2 < 5; ++t2) { e[t2] = __expf(lgt[t2] - mx); sum += e[t2]; }
    float inv = 1.f / sum;
    float* outp = edge_out + ((size_t)m * NPAIR + p) * 5;
    #pragma unroll
    for (int t2 = 0; t2 < 5; ++t2) outp[t2] = e[t2] * inv;
  }
}

extern "C" void kernel_launch(void* const* d_in, const int* in_sizes, int n_in,
                              void* d_out, int out_size, void* d_ws, size_t ws_size,
                              hipStream_t stream) {
  const float* eta    = (const float*)d_in[0];
  const float* gumbel = (const float*)d_in[1];
  const float* z_noise= (const float*)d_in[2];
  const float* cW1 = (const float*)d_in[3];
  const float* cb1 = (const float*)d_in[4];
  const float* cW2 = (const float*)d_in[5];
  const float* cb2 = (const float*)d_in[6];
  const float* cWs = (const float*)d_in[7];
  const float* cbs = (const float*)d_in[8];
  const float* means = (const float*)d_in[9];
  const float* lsig  = (const float*)d_in[10];
  const float* aW1 = (const float*)d_in[11];
  const float* ab1 = (const float*)d_in[12];
  const float* aW2 = (const float*)d_in[13];
  const float* ab2 = (const float*)d_in[14];
  const float* aWs = (const float*)d_in[15];
  const float* abs_= (const float*)d_in[16];
  const float* bond= (const float*)d_in[17];
  const float* bW1 = (const float*)d_in[18];
  const float* bb1 = (const float*)d_in[19];
  const float* bW2 = (const float*)d_in[20];
  const float* bb2 = (const float*)d_in[21];
  const float* bWs = (const float*)d_in[22];
  const float* bbs = (const float*)d_in[23];

  float* wsym   = (float*)d_ws;          // 5120
  float* sigma  = wsym + 5120;           // 1024
  float* hwg    = sigma + 1024;          // 744 (+pad)
  float* log_pi = hwg + 768;             // 1024*32
  float* atom_out = (float*)d_out;                    // 1024*400
  float* edge_out = atom_out + (size_t)1024 * 400;    // 1024*780*5

  prep_kernel<<<284, 256, 0, stream>>>(eta, cW1, cb1, cW2, cb2, cWs, cbs,
                                       bond, lsig, bW1, bb1, bW2, bb2, bWs, bbs,
                                       log_pi, wsym, sigma, hwg);
  fused_kernel<<<1024, 256, 0, stream>>>(log_pi, gumbel, z_noise,
                                         means, sigma, aW1, ab1, aW2, ab2, aWs, abs_,
                                         wsym, hwg, atom_out, edge_out);
}